// Round 8
// baseline (294.710 us; speedup 1.0000x reference)
//
#include <hip/hip_runtime.h>
#include <hip/hip_bf16.h>
#include <hip/hip_fp16.h>

#define N_NODES   100000
#define N_EDGES   1600000
#define N_GRAPHS  1024
#define EMB       32
#define HID       64
#define N_CLASSES 10
#define SCAN_BLOCKS 391   // ceil(100000/256)
#define NCOMBO 153        // 17 shape ids x 9 color ids
#define SLOT 64           // fixed in-edge slots per node (P(deg>64) ~ 0 for Poisson(16))

typedef _Float16 f16x8 __attribute__((ext_vector_type(8)));
typedef float f32x4 __attribute__((ext_vector_type(4)));

// ---------------- prep: combo[v] + batch boundaries + TC table + zero cnt/pooled ----------------
__global__ __launch_bounds__(256) void prep_kernel(
    const int* __restrict__ sid, const int* __restrict__ cid,
    const int* __restrict__ batch, int* __restrict__ combo, int* __restrict__ gstart,
    const float* __restrict__ st, const float* __restrict__ ct,
    const float* __restrict__ W1, __half* __restrict__ TCh,
    float* __restrict__ pooled, int* __restrict__ cnt) {
    int t = threadIdx.x;
    int v = blockIdx.x * 256 + t;
    if (v < N_GRAPHS * HID) pooled[v] = 0.0f;
    if (v < N_NODES) {
        cnt[v] = 0;
        combo[v] = sid[v] * 9 + cid[v];
        int b = batch[v];
        int bp = (v == 0) ? -1 : batch[v - 1];
        for (int g = bp + 1; g <= b; ++g) gstart[g] = v;      // boundary (usually 0 iters)
        if (v == N_NODES - 1) {
            for (int g = b + 1; g <= N_GRAPHS; ++g) gstart[g] = N_NODES;
        }
    }
    // TC table: TCh[s*9+c][j] = (st[s]@W1)[j] + (ct[c]@W1)[j]  (fp16)
    if (blockIdx.x < NCOMBO && t >= 64 && t < 128) {
        int r = blockIdx.x, j = t - 64;
        int s = r / 9, c = r % 9;
        float acc = 0.0f;
        if (s != 0) {
#pragma unroll
            for (int k = 0; k < EMB; ++k) acc = fmaf(st[s * EMB + k], W1[k * HID + j], acc);
        }
        if (c != 0) {
#pragma unroll
            for (int k = 0; k < EMB; ++k) acc = fmaf(ct[c * EMB + k], W1[k * HID + j], acc);
        }
        TCh[r * HID + j] = __float2half_rn(acc);
    }
}

// ---------------- scatter: direct fixed-slot CSR build via distributed global atomics ----------------
// cnt[dst] after this kernel == in-degree(dst).  1.6M atomics over 100k addresses
// (avg 16/address - low contention, executed L2-side).  All ~400k threads resident
// at once -> one latency chain deep.  epackF row v = srcs of v's in-edges.
__global__ __launch_bounds__(256) void scatter_kernel(
    const int* __restrict__ src, const int* __restrict__ dst,
    int* __restrict__ cnt, int* __restrict__ epackF) {
    int t = blockIdx.x * 256 + threadIdx.x;
    int e = t * 4;
    if (e >= N_EDGES) return;
    int4 s4 = *(const int4*)&src[e];
    int4 d4 = *(const int4*)&dst[e];
    int p0 = atomicAdd(&cnt[d4.x], 1);
    int p1 = atomicAdd(&cnt[d4.y], 1);
    int p2 = atomicAdd(&cnt[d4.z], 1);
    int p3 = atomicAdd(&cnt[d4.w], 1);
    if (p0 < SLOT) epackF[(d4.x << 6) + p0] = s4.x;
    if (p1 < SLOT) epackF[(d4.y << 6) + p1] = s4.y;
    if (p2 < SLOT) epackF[(d4.z << 6) + p2] = s4.z;
    if (p3 < SLOT) epackF[(d4.w << 6) + p3] = s4.w;
}

// ---------------- fused layer-1 aggregate + MFMA mm2 ----------------
// Block = 16 consecutive nodes; wave w owns nodes v0..v0+3 for aggregation.
// Edge prefetch: lanes 16n..16n+15 hold slots 0-15 (q1x) and 16-31 (q2x) of node
// v0+n; dis = rsqrt(1+cnt[src]) and combo[src]<<7 gathered per-lane (L2-resident).
// Slots >= deg hold garbage: src masked &0x1FFFF (bounded), value masked to 0.
// mm2: block-cooperative X(16x64,fp16) @ W2(64x64,fp16) via 2x mfma_f32_16x16x32_f16.
#define AGG_CHUNK(CQ, DQ, LBASE, J0)                                           \
    _Pragma("unroll")                                                          \
    for (int i = 0; i < 8; ++i) {                                              \
        int off = __builtin_amdgcn_readlane((CQ), (LBASE) + i) & 0x7FFF;       \
        int wb  = __builtin_amdgcn_readlane(__float_as_int(DQ), (LBASE) + i);  \
        off = ((J0) + i < ccnt) ? off : 0;                                     \
        wb  = ((J0) + i < ccnt) ? wb  : 0;                                     \
        __half tv = *(const __half*)((const char*)TCs + (off + lane2));        \
        acc = fmaf(__int_as_float(wb), __half2float(tv), acc);                 \
    }

#define AGG_NODE(N, DEG, DV, CO)                                               \
    {                                                                          \
        int deg = (DEG);                                                       \
        int ccnt = deg > 32 ? 32 : deg;                                        \
        float acc = 0.0f;                                                      \
        AGG_CHUNK(cq1, dq1, (N)*16, 0)                                         \
        if (ccnt > 8)  { AGG_CHUNK(cq1, dq1, (N)*16 + 8, 8) }                  \
        if (ccnt > 16) { AGG_CHUNK(cq2, dq2, (N)*16, 16) }                     \
        if (ccnt > 24) { AGG_CHUNK(cq2, dq2, (N)*16 + 8, 24) }                 \
        if (deg > 32) {                                                        \
            int ebase = (v0 + (N)) << 6;                                       \
            for (int e = 32; e < deg; ++e) {                                   \
                int qx = epackF[ebase + e] & 0x1FFFF;                          \
                float dw = rsqrtf(1.0f + (float)cnt[qx]);                      \
                __half tv = *(const __half*)((const char*)TCs +                \
                                             ((combo[qx] << 7) + lane2));      \
                acc = fmaf(dw, __half2float(tv), acc);                         \
            }                                                                  \
        }                                                                      \
        __half hv = *(const __half*)((const char*)TCs + ((CO) + lane2));       \
        float val = (DV) * fmaf(__half2float(hv), (DV), acc) + bias;           \
        val = val > 0.0f ? val : 0.0f;                                         \
        xsA[w * 4 + (N)][lane] = __float2half_rn(val * (DV));                  \
    }

__global__ __launch_bounds__(256, 6) void agg1_mm2_kernel(
    const int* __restrict__ epackF, const int* __restrict__ cnt,
    const int* __restrict__ combo,
    const __half* __restrict__ TCh, const float* __restrict__ W2,
    const float* __restrict__ b1, __half* __restrict__ h2s) {
    __shared__ __align__(16) __half TCs[NCOMBO * HID];  // 19,584 B
    __shared__ __align__(16) __half xsA[16][72];        //  2,304 B (stride 72: bank spread)
    __shared__ __align__(16) __half Dst[16 * 64];       //  2,048 B
    int t = threadIdx.x;
    int lane = t & 63, w = t >> 6;
    int lane2 = lane * 2;
    int vb = blockIdx.x * 16;
    int v0 = vb + w * 4;

    // per-lane sliced edge prefetch (longest latency chain - issue first)
    int sub = lane >> 4, sl = lane & 15;
    int rb = (v0 + sub) << 6;
    int q1x = epackF[rb + sl] & 0x1FFFF;        // node sub, slots 0..15 (mask garbage)
    int q2x = epackF[rb + 16 + sl] & 0x1FFFF;   // node sub, slots 16..31
    float dq1 = rsqrtf(1.0f + (float)cnt[q1x]); // dependent gathers, L2-resident
    float dq2 = rsqrtf(1.0f + (float)cnt[q2x]);
    int cq1 = combo[q1x] << 7;                  // TC byte offset
    int cq2 = combo[q2x] << 7;

    // per-node degrees (wave-uniform)
    int c0 = __builtin_amdgcn_readfirstlane(cnt[v0]);
    int c1 = __builtin_amdgcn_readfirstlane(cnt[v0 + 1]);
    int c2 = __builtin_amdgcn_readfirstlane(cnt[v0 + 2]);
    int c3 = __builtin_amdgcn_readfirstlane(cnt[v0 + 3]);
    c0 = c0 > SLOT ? SLOT : c0;
    c1 = c1 > SLOT ? SLOT : c1;
    c2 = c2 > SLOT ? SLOT : c2;
    c3 = c3 > SLOT ? SLOT : c3;

    // per-node epilogue scalars
    float d0 = rsqrtf(1.0f + (float)c0), d1 = rsqrtf(1.0f + (float)c1);
    float d2 = rsqrtf(1.0f + (float)c2), d3 = rsqrtf(1.0f + (float)c3);
    int o0 = combo[v0] << 7, o1 = combo[v0 + 1] << 7;
    int o2 = combo[v0 + 2] << 7, o3 = combo[v0 + 3] << 7;
    float bias = b1[lane];

    // B fragments of W2 for this wave's 16 output cols (built once, from global)
    f16x8 bf0, bf1;
    {
        int colw = (w << 4) + (lane & 15);
        int kb = (lane >> 4) * 8;
#pragma unroll
        for (int i = 0; i < 8; ++i) {
            bf0[i] = (_Float16)W2[(kb + i) * HID + colw];
            bf1[i] = (_Float16)W2[(32 + kb + i) * HID + colw];
        }
    }

    // stage TC table to LDS
    {
        const int4* s4 = (const int4*)TCh;
        int4* dd4 = (int4*)TCs;
        for (int i = t; i < NCOMBO * HID * 2 / 16; i += 256) dd4[i] = s4[i];
    }
    __syncthreads();   // also drains the edge + cnt + combo prefetch

    AGG_NODE(0, c0, d0, o0)
    AGG_NODE(1, c1, d1, o1)
    AGG_NODE(2, c2, d2, o2)
    AGG_NODE(3, c3, d3, o3)

    __syncthreads();   // all 16 rows of xsA ready

    // A fragments: row = lane&15 (node), k = (lane>>4)*8 + i  (+32 for 2nd MFMA)
    const __half* xa = &xsA[lane & 15][0];
    f16x8 a0 = *(const f16x8*)(xa + (lane >> 4) * 8);
    f16x8 a1 = *(const f16x8*)(xa + 32 + (lane >> 4) * 8);
    f32x4 dacc = {0.0f, 0.0f, 0.0f, 0.0f};
    dacc = __builtin_amdgcn_mfma_f32_16x16x32_f16(a0, bf0, dacc, 0, 0, 0);
    dacc = __builtin_amdgcn_mfma_f32_16x16x32_f16(a1, bf1, dacc, 0, 0, 0);

    // D: col = lane&15 (within wave's 16-col block), row = (lane>>4)*4 + i (node)
    {
        int colg = (w << 4) + (lane & 15);
#pragma unroll
        for (int i = 0; i < 4; ++i)
            Dst[((lane >> 4) * 4 + i) * 64 + colg] = __float2half_rn(dacc[i]);
    }
    __syncthreads();

    // coalesced block store: 16 nodes x 64 feats fp16 = 2048 B contiguous
    {
        const uint2* ds2 = (const uint2*)Dst;
        uint2* go = (uint2*)(h2s + (size_t)vb * HID);
        go[t] = ds2[t];
    }
}

// ---------------- per-node edge accumulate for layer 2 ----------------
// sx: lane i holds epackF[v*64+i] (masked src).  Broadcast h2s byte-offset per
// edge via readlane; gathers are per-lane 2B loads (vmcnt, 8-deep in flight).
// cn <= 64, so a single 64-slot pass suffices.
__device__ __forceinline__ float agg2_node(int sx, int cn, int lane2,
                                           const __half* __restrict__ h2s) {
    float acc = 0.0f;
    int vo = sx << 7;                  // src*128 byte offset
    int j = 0;
    for (; j + 8 <= cn; j += 8) {
        float g[8];
#pragma unroll
        for (int i = 0; i < 8; ++i) {
            int off = __builtin_amdgcn_readlane(vo, j + i);
            g[i] = __half2float(*(const __half*)((const char*)h2s + (off + lane2)));
        }
#pragma unroll
        for (int i = 0; i < 8; ++i) acc += g[i];
    }
    if (j < cn) {
#pragma unroll
        for (int i = 0; i < 8; ++i) {
            int jj = j + i;
            int off = __builtin_amdgcn_readlane(vo, jj & 63);
            float gv = __half2float(*(const __half*)((const char*)h2s + (off + lane2)));
            acc += (jj < cn) ? gv : 0.0f;
        }
    }
    return acc;
}

// ---------------- layer-2 aggregate + pool: 4 nodes/wave, run-merged atomics ----------------
__global__ __launch_bounds__(256, 8) void agg2_pool_kernel(
    const int* __restrict__ epackF, const int* __restrict__ cnt,
    const __half* __restrict__ h2s,
    const float* __restrict__ b2, const int* __restrict__ batch,
    float* __restrict__ pooled) {
    int t = threadIdx.x, lane = t & 63, w = t >> 6;
    int lane2 = lane * 2;
    int v0 = (blockIdx.x * 4 + w) * 4;   // grid 6250

    int c0r = __builtin_amdgcn_readfirstlane(cnt[v0]);
    int c1r = __builtin_amdgcn_readfirstlane(cnt[v0 + 1]);
    int c2r = __builtin_amdgcn_readfirstlane(cnt[v0 + 2]);
    int c3r = __builtin_amdgcn_readfirstlane(cnt[v0 + 3]);
    int c0 = c0r > SLOT ? SLOT : c0r;
    int c1 = c1r > SLOT ? SLOT : c1r;
    int c2 = c2r > SLOT ? SLOT : c2r;
    int c3 = c3r > SLOT ? SLOT : c3r;

    int sa = epackF[(v0 << 6) + lane] & 0x1FFFF;
    int sb = epackF[((v0 + 1) << 6) + lane] & 0x1FFFF;
    int sc = epackF[((v0 + 2) << 6) + lane] & 0x1FFFF;
    int sd = epackF[((v0 + 3) << 6) + lane] & 0x1FFFF;

    float bv = b2[lane];
    float acc0 = agg2_node(sa, c0, lane2, h2s);
    float acc1 = agg2_node(sb, c1, lane2, h2s);
    float acc2 = agg2_node(sc, c2, lane2, h2s);
    float acc3 = agg2_node(sd, c3, lane2, h2s);

#define AGG2_VAL(V, CR, ACC, OUT)                                              \
    {                                                                          \
        float dv = rsqrtf(1.0f + (float)(CR));                                 \
        float self = __half2float(h2s[(size_t)(V) * HID + lane]);              \
        float val = dv * ((ACC) + self) + bv;                                  \
        OUT = val > 0.0f ? val : 0.0f;                                         \
    }
    float val0, val1, val2, val3;
    AGG2_VAL(v0, c0r, acc0, val0)
    AGG2_VAL(v0 + 1, c1r, acc1, val1)
    AGG2_VAL(v0 + 2, c2r, acc2, val2)
    AGG2_VAL(v0 + 3, c3r, acc3, val3)
#undef AGG2_VAL

    int g0 = __builtin_amdgcn_readfirstlane(batch[v0]);
    int g1 = __builtin_amdgcn_readfirstlane(batch[v0 + 1]);
    int g2 = __builtin_amdgcn_readfirstlane(batch[v0 + 2]);
    int g3 = __builtin_amdgcn_readfirstlane(batch[v0 + 3]);
    // batch is sorted: merge same-graph contributions into one atomic per run
    float s = val0; int g = g0;
    if (g1 == g) { s += val1; } else { unsafeAtomicAdd(&pooled[g * HID + lane], s); g = g1; s = val1; }
    if (g2 == g) { s += val2; } else { unsafeAtomicAdd(&pooled[g * HID + lane], s); g = g2; s = val2; }
    if (g3 == g) { s += val3; } else { unsafeAtomicAdd(&pooled[g * HID + lane], s); g = g3; s = val3; }
    unsafeAtomicAdd(&pooled[g * HID + lane], s);
}

// ---------------- logits ----------------
__global__ __launch_bounds__(64) void logits_kernel(
    const float* __restrict__ pooled, const int* __restrict__ gstart,
    const float* __restrict__ Wl, const float* __restrict__ bl,
    float* __restrict__ out) {
    __shared__ float row[HID];
    int g = blockIdx.x, t = threadIdx.x;
    int c = gstart[g + 1] - gstart[g]; if (c < 1) c = 1;
    row[t] = pooled[g * HID + t] / (float)c;
    __syncthreads();
    if (t < N_CLASSES) {
        float acc = bl[t];
#pragma unroll
        for (int k = 0; k < HID; ++k) acc = fmaf(row[k], Wl[k * N_CLASSES + t], acc);
        out[g * N_CLASSES + t] = acc;
    }
}

extern "C" void kernel_launch(void* const* d_in, const int* in_sizes, int n_in,
                              void* d_out, int out_size, void* d_ws, size_t ws_size,
                              hipStream_t stream) {
    const int*   shape_id = (const int*)d_in[0];
    const int*   color_id = (const int*)d_in[1];
    const int*   edge_idx = (const int*)d_in[2];
    const int*   batch    = (const int*)d_in[3];
    const float* st       = (const float*)d_in[4];
    const float* ct       = (const float*)d_in[5];
    const float* W1       = (const float*)d_in[6];
    const float* b1       = (const float*)d_in[7];
    const float* W2       = (const float*)d_in[8];
    const float* b2       = (const float*)d_in[9];
    const float* Wl       = (const float*)d_in[10];
    const float* bl       = (const float*)d_in[11];
    float* out = (float*)d_out;

    const int* src = edge_idx;
    const int* dst = edge_idx + N_EDGES;

    // workspace layout
    char* ws = (char*)d_ws;
    int*    combo   = (int*)   (ws + 0);            //   400,384 B
    int*    gstart  = (int*)   (ws + 801792);       //     4,112 B
    int*    cnt     = (int*)   (ws + 1201152);      //   400,384 B (in-degree / scatter cursor)
    __half* TCh     = (__half*)(ws + 1603584);      //    19,968 B
    float*  pooled  = (float*) (ws + 1623552);      //   262,144 B
    int*    epackF  = (int*)   (ws + 1890816);      // 25,600,000 B (100k x 64 slots x 4B)
    __half* h2s     = (__half*)(ws + 29370880);     // 12,800,000 B (total ~42.2 MB)

    // 1. combo + batch boundaries + TC table + pooled/cnt zeroing (fused)
    prep_kernel<<<SCAN_BLOCKS, 256, 0, stream>>>(shape_id, color_id, batch, combo, gstart,
                                                 st, ct, W1, TCh, pooled, cnt);

    // 2. direct fixed-slot scatter (replaces binA + bucket_scatter entirely)
    scatter_kernel<<<(N_EDGES / 4 + 255) / 256, 256, 0, stream>>>(src, dst, cnt, epackF);

    // 3. fused layer-1 aggregate + MFMA mm2 -> h2s (16 nodes/block)
    agg1_mm2_kernel<<<6250, 256, 0, stream>>>(epackF, cnt, combo, TCh, W2, b1, h2s);

    // 4. layer-2 aggregate + pool (8 waves/EU, fixed-stride rows)
    agg2_pool_kernel<<<6250, 256, 0, stream>>>(epackF, cnt, h2s, b2, batch, pooled);

    // 5. logits (counts from gstart boundaries)
    logits_kernel<<<N_GRAPHS, 64, 0, stream>>>(pooled, gstart, Wl, bl, out);
}

// Round 10
// 185.887 us; speedup vs baseline: 1.5854x; 1.5854x over previous
//
#include <hip/hip_runtime.h>
#include <hip/hip_bf16.h>
#include <hip/hip_fp16.h>

#define N_NODES   100000
#define N_EDGES   1600000
#define N_GRAPHS  1024
#define EMB       32
#define HID       64
#define N_CLASSES 10
#define SCAN_BLOCKS 391   // ceil(100000/256)
#define NCOMBO 153        // 17 shape ids x 9 color ids
#define BUCK_NODES 448    // nodes per dst-bucket
#define NBUCK 224         // ceil(100000/448)
#define BIN_CAP 8192      // per-bucket staging capacity (mean 7143, +12 sigma)
#define EPB 4096          // edges per binA block

typedef _Float16 f16x8 __attribute__((ext_vector_type(8)));
typedef float f32x4 __attribute__((ext_vector_type(4)));

// ---------------- prep: combo[v] + batch boundaries + TC table + buffer zeroing ----------------
__global__ __launch_bounds__(256) void prep_kernel(
    const int* __restrict__ sid, const int* __restrict__ cid,
    const int* __restrict__ batch, int* __restrict__ combo, int* __restrict__ gstart,
    const float* __restrict__ st, const float* __restrict__ ct,
    const float* __restrict__ W1, __half* __restrict__ TCh,
    float* __restrict__ pooled, int* __restrict__ gcur) {
    int t = threadIdx.x;
    int v = blockIdx.x * 256 + t;
    if (v < N_GRAPHS * HID) pooled[v] = 0.0f;
    if (blockIdx.x == 0 && t < NBUCK) gcur[t] = 0;
    if (v < N_NODES) {
        combo[v] = sid[v] * 9 + cid[v];
        int b = batch[v];
        int bp = (v == 0) ? -1 : batch[v - 1];
        for (int g = bp + 1; g <= b; ++g) gstart[g] = v;      // boundary (usually 0 iters)
        if (v == N_NODES - 1) {
            for (int g = b + 1; g <= N_GRAPHS; ++g) gstart[g] = N_NODES;
        }
    }
    // TC table: TCh[s*9+c][j] = (st[s]@W1)[j] + (ct[c]@W1)[j]  (fp16)
    if (blockIdx.x < NCOMBO && t >= 64 && t < 128) {
        int r = blockIdx.x, j = t - 64;
        int s = r / 9, c = r % 9;
        float acc = 0.0f;
        if (s != 0) {
#pragma unroll
            for (int k = 0; k < EMB; ++k) acc = fmaf(st[s * EMB + k], W1[k * HID + j], acc);
        }
        if (c != 0) {
#pragma unroll
            for (int k = 0; k < EMB; ++k) acc = fmaf(ct[c * EMB + k], W1[k * HID + j], acc);
        }
        TCh[r * HID + j] = __float2half_rn(acc);
    }
}

// ---------------- binA: block-local counting sort by dst-bucket, packed single-plane flush ----------------
// gbin[e] = src | (local_dst << 17)   [src: 17b, local dst within bucket: 9b]
// Halves binA's global writes and bucket_scatter's reads vs two planes.
__global__ __launch_bounds__(512) void binA_kernel(
    const int* __restrict__ src, const int* __restrict__ dst,
    int* __restrict__ gcur, int* __restrict__ gbin) {
    __shared__ int2 stg[EPB];            // 32 KB
    __shared__ int hist[NBUCK];
    __shared__ int base[NBUCK + 1];
    __shared__ int gstart[NBUCK];
    __shared__ int scanbuf[256];
    int t = threadIdx.x;
    int e0 = blockIdx.x * EPB;
    for (int i = t; i < NBUCK; i += 512) hist[i] = 0;
    __syncthreads();

    int2 myq[8];
    int mybo[8];
    if (e0 + EPB <= N_EDGES) {
        int eb = e0 + t * 8;
        int4 sa4 = *(const int4*)&src[eb];
        int4 sb4 = *(const int4*)&src[eb + 4];
        int4 da4 = *(const int4*)&dst[eb];
        int4 db4 = *(const int4*)&dst[eb + 4];
        int ss[8] = {sa4.x, sa4.y, sa4.z, sa4.w, sb4.x, sb4.y, sb4.z, sb4.w};
        int dd[8] = {da4.x, da4.y, da4.z, da4.w, db4.x, db4.y, db4.z, db4.w};
#pragma unroll
        for (int i = 0; i < 8; ++i) {
            unsigned b = (unsigned)dd[i] / BUCK_NODES;
            int off = atomicAdd(&hist[b], 1);
            myq[i].x = ss[i];
            myq[i].y = dd[i];
            mybo[i] = (int)(b << 16) | off;
        }
    } else {
#pragma unroll
        for (int i = 0; i < 8; ++i) {
            int e = e0 + t * 8 + i;
            if (e < N_EDGES) {
                int d = dst[e];
                unsigned b = (unsigned)d / BUCK_NODES;
                int off = atomicAdd(&hist[b], 1);
                myq[i].x = src[e];
                myq[i].y = d;
                mybo[i] = (int)(b << 16) | off;
            } else {
                mybo[i] = -1;
            }
        }
    }
    __syncthreads();

    int h = (t < NBUCK) ? hist[t] : 0;
    if (t < 256) scanbuf[t] = h;
    __syncthreads();
#pragma unroll
    for (int off = 1; off < 256; off <<= 1) {
        int x = (t < 256 && t >= off) ? scanbuf[t - off] : 0;
        __syncthreads();
        if (t < 256) scanbuf[t] += x;
        __syncthreads();
    }
    if (t < NBUCK) base[t] = scanbuf[t] - h;
    if (t == 0) base[NBUCK] = scanbuf[255];
    __syncthreads();
#pragma unroll
    for (int i = 0; i < 8; ++i) {
        if (mybo[i] >= 0) {
            int b = mybo[i] >> 16, off = mybo[i] & 0xFFFF;
            stg[base[b] + off] = myq[i];
        }
    }
    if (t < NBUCK) {
        int n = hist[t];
        gstart[t] = n ? atomicAdd(&gcur[t], n) : 0;
    }
    __syncthreads();
    int total = base[NBUCK];
    for (int i = t; i < total; i += 512) {
        int2 q = stg[i];
        unsigned b = (unsigned)q.y / BUCK_NODES;
        int local = q.y - (int)b * BUCK_NODES;          // < 448, 9 bits
        gbin[(size_t)b * BIN_CAP + gstart[b] + (i - base[b])] = q.x | (local << 17);
    }
}

// ---------------- bucket_scatter: degrees + dis + rowptr + CSR scatter (merged, 1 global read) ----------------
// Pass 1: stream packed gbin (int4) -> LDS stage + degree count (p>>17 = local dst).
// Scan -> dis/rowptr/rbase.  Pass 2: pure-LDS re-read, scatter dense 4B src records.
// epack4[e] = src
__global__ __launch_bounds__(1024) void bucket_scatter_kernel(
    const int* __restrict__ gbin, const int* __restrict__ gcur,
    float* __restrict__ dis, int* __restrict__ rowptr, int* __restrict__ epack4) {
    __shared__ __align__(16) int pbin[BIN_CAP];   // 32 KB: staged packed plane
    __shared__ int ldeg[BUCK_NODES];              // degree count, then scatter cursors
    __shared__ int rbase[BUCK_NODES];             // per-node CSR base
    __shared__ int s[512];
    __shared__ int sc[256];
    int b = blockIdx.x, t = threadIdx.x;
    if (t < 256) sc[t] = (t < NBUCK) ? gcur[t] : 0;
    for (int i = t; i < BUCK_NODES; i += 1024) ldeg[i] = 0;
    __syncthreads();
    // inclusive scan of gcur -> bucket base
#pragma unroll
    for (int off = 1; off < 256; off <<= 1) {
        int x = (t < 256 && t >= off) ? sc[t - off] : 0;
        __syncthreads();
        if (t < 256) sc[t] += x;
        __syncthreads();
    }
    int bb = (b == 0) ? 0 : sc[b - 1];
    int n = gcur[b];
    int nc = (n + 3) >> 2;
    // pass 1: stage packed plane + count degrees (int4 stream)
    {
        const int4* my4 = (const int4*)(gbin + (size_t)b * BIN_CAP);
        for (int c = t; c < nc; c += 1024) {
            int4 p4 = my4[c];
            ((int4*)pbin)[c] = p4;
            int i0 = c * 4;
            if (i0 + 0 < n) atomicAdd(&ldeg[(unsigned)p4.x >> 17], 1);
            if (i0 + 1 < n) atomicAdd(&ldeg[(unsigned)p4.y >> 17], 1);
            if (i0 + 2 < n) atomicAdd(&ldeg[(unsigned)p4.z >> 17], 1);
            if (i0 + 3 < n) atomicAdd(&ldeg[(unsigned)p4.w >> 17], 1);
        }
    }
    __syncthreads();
    int d = (t < BUCK_NODES) ? ldeg[t] : 0;
    int v = b * BUCK_NODES + t;
    if (t < BUCK_NODES && v < N_NODES) dis[v] = rsqrtf(1.0f + (float)d);
    if (t < 512) s[t] = d;
    __syncthreads();
#pragma unroll
    for (int off = 1; off < 512; off <<= 1) {
        int x = (t < 512 && t >= off) ? s[t - off] : 0;
        __syncthreads();
        if (t < 512) s[t] += x;
        __syncthreads();
    }
    if (t < BUCK_NODES) {
        int rp = bb + s[t] - d;
        rbase[t] = rp;
        if (v < N_NODES) rowptr[v] = rp;
    }
    if (b == 0 && t == 0) rowptr[N_NODES] = N_EDGES;
    // reset cursors
    for (int i = t; i < BUCK_NODES; i += 1024) ldeg[i] = 0;
    __syncthreads();
    // pass 2: pure-LDS scatter (dense writes within bucket's CSR region)
    for (int i = t; i < n; i += 1024) {
        int p = pbin[i];
        int local = (unsigned)p >> 17;
        int r = atomicAdd(&ldeg[local], 1);
        epack4[rbase[local] + r] = p & 0x1FFFF;
    }
}

// ---------------- fused layer-1 aggregate + MFMA mm2 ----------------
// Block = 16 consecutive nodes; wave w owns nodes v0..v0+3 for aggregation.
// Edge prefetch: lanes 16n..16n+15 hold src words 0-15 (q1x) and 16-31 (q2x) of
// node n; dis[src] and combo[src]<<7 gathered per-lane (both L2-resident).
// Edge consume: readlane broadcast of TC offset + weight, LDS TC gather.
// mm2: block-cooperative X(16x64,fp16) @ W2(64x64,fp16) via 2x mfma_f32_16x16x32_f16.
#define AGG_CHUNK(CQ, DQ, LBASE, J0)                                           \
    _Pragma("unroll")                                                          \
    for (int i = 0; i < 8; ++i) {                                              \
        int off = __builtin_amdgcn_readlane((CQ), (LBASE) + i) & 0x7FFF;       \
        int wb  = __builtin_amdgcn_readlane(__float_as_int(DQ), (LBASE) + i);  \
        off = ((J0) + i < cnt) ? off : 0;                                      \
        wb  = ((J0) + i < cnt) ? wb  : 0;                                      \
        __half tv = *(const __half*)((const char*)TCs + (off + lane2));        \
        acc = fmaf(__int_as_float(wb), __half2float(tv), acc);                 \
    }

#define AGG_NODE(N, RS, RE, DV, CO)                                            \
    {                                                                          \
        int deg = (RE) - (RS);                                                 \
        int cnt = deg > 32 ? 32 : deg;                                         \
        float acc = 0.0f;                                                      \
        AGG_CHUNK(cq1, dq1, (N)*16, 0)                                         \
        if (cnt > 8)  { AGG_CHUNK(cq1, dq1, (N)*16 + 8, 8) }                   \
        if (cnt > 16) { AGG_CHUNK(cq2, dq2, (N)*16, 16) }                      \
        if (cnt > 24) { AGG_CHUNK(cq2, dq2, (N)*16 + 8, 24) }                  \
        if (deg > 32) {                                                        \
            for (int e = (RS) + 32; e < (RE); ++e) {                           \
                int qx = epack4[e];                                            \
                float dw = dis[qx];                                            \
                __half tv = *(const __half*)((const char*)TCs +                \
                                             ((combo[qx] << 7) + lane2));      \
                acc = fmaf(dw, __half2float(tv), acc);                         \
            }                                                                  \
        }                                                                      \
        __half hv = *(const __half*)((const char*)TCs + ((CO) + lane2));       \
        float val = (DV) * fmaf(__half2float(hv), (DV), acc) + bias;           \
        val = val > 0.0f ? val : 0.0f;                                         \
        xsA[w * 4 + (N)][lane] = __float2half_rn(val * (DV));                  \
    }

__global__ __launch_bounds__(256, 6) void agg1_mm2_kernel(
    const int* __restrict__ epack4, const int* __restrict__ rowptr,
    const int* __restrict__ combo, const float* __restrict__ dis,
    const __half* __restrict__ TCh, const float* __restrict__ W2,
    const float* __restrict__ b1, __half* __restrict__ h2s) {
    __shared__ __align__(16) __half TCs[NCOMBO * HID];  // 19,584 B
    __shared__ __align__(16) __half xsA[16][72];        //  2,304 B (stride 72: bank spread)
    __shared__ __align__(16) __half Dst[16 * 64];       //  2,048 B
    int t = threadIdx.x;
    int lane = t & 63, w = t >> 6;
    int lane2 = lane * 2;
    int vb = blockIdx.x * 16;
    int v0 = vb + w * 4;

    // per-lane sliced edge prefetch (longest latency chain - issue first)
    int sub = lane >> 4, sl = lane & 15;
    int rb = rowptr[v0 + sub];
    int q1x = epack4[rb + sl] & 0x1FFFF;        // node sub, edges 0..15 (mask bounds garbage)
    int q2x = epack4[rb + 16 + sl] & 0x1FFFF;   // node sub, edges 16..31 (may over-read: ok)
    float dq1 = dis[q1x];                       // dependent gathers, L2-resident
    float dq2 = dis[q2x];
    int cq1 = combo[q1x] << 7;                  // TC byte offset
    int cq2 = combo[q2x] << 7;

    // scalar row pointers
    int r0 = __builtin_amdgcn_readfirstlane(rowptr[v0]);
    int r1 = __builtin_amdgcn_readfirstlane(rowptr[v0 + 1]);
    int r2 = __builtin_amdgcn_readfirstlane(rowptr[v0 + 2]);
    int r3 = __builtin_amdgcn_readfirstlane(rowptr[v0 + 3]);
    int r4 = __builtin_amdgcn_readfirstlane(rowptr[v0 + 4]);

    // per-node epilogue scalars (issue early)
    float d0 = dis[v0], d1 = dis[v0 + 1], d2 = dis[v0 + 2], d3 = dis[v0 + 3];
    int o0 = combo[v0] << 7, o1 = combo[v0 + 1] << 7;
    int o2 = combo[v0 + 2] << 7, o3 = combo[v0 + 3] << 7;
    float bias = b1[lane];

    // B fragments of W2 for this wave's 16 output cols (built once, from global)
    f16x8 bf0, bf1;
    {
        int colw = (w << 4) + (lane & 15);
        int kb = (lane >> 4) * 8;
#pragma unroll
        for (int i = 0; i < 8; ++i) {
            bf0[i] = (_Float16)W2[(kb + i) * HID + colw];
            bf1[i] = (_Float16)W2[(32 + kb + i) * HID + colw];
        }
    }

    // stage TC table to LDS
    {
        const int4* s4 = (const int4*)TCh;
        int4* dd4 = (int4*)TCs;
        for (int i = t; i < NCOMBO * HID * 2 / 16; i += 256) dd4[i] = s4[i];
    }
    __syncthreads();   // also drains the edge + dis + combo prefetch

    AGG_NODE(0, r0, r1, d0, o0)
    AGG_NODE(1, r1, r2, d1, o1)
    AGG_NODE(2, r2, r3, d2, o2)
    AGG_NODE(3, r3, r4, d3, o3)

    __syncthreads();   // all 16 rows of xsA ready

    // A fragments: row = lane&15 (node), k = (lane>>4)*8 + i  (+32 for 2nd MFMA)
    const __half* xa = &xsA[lane & 15][0];
    f16x8 a0 = *(const f16x8*)(xa + (lane >> 4) * 8);
    f16x8 a1 = *(const f16x8*)(xa + 32 + (lane >> 4) * 8);
    f32x4 dacc = {0.0f, 0.0f, 0.0f, 0.0f};
    dacc = __builtin_amdgcn_mfma_f32_16x16x32_f16(a0, bf0, dacc, 0, 0, 0);
    dacc = __builtin_amdgcn_mfma_f32_16x16x32_f16(a1, bf1, dacc, 0, 0, 0);

    // D: col = lane&15 (within wave's 16-col block), row = (lane>>4)*4 + i (node)
    {
        int colg = (w << 4) + (lane & 15);
#pragma unroll
        for (int i = 0; i < 4; ++i)
            Dst[((lane >> 4) * 4 + i) * 64 + colg] = __float2half_rn(dacc[i]);
    }
    __syncthreads();

    // coalesced block store: 16 nodes x 64 feats fp16 = 2048 B contiguous
    {
        const uint2* ds2 = (const uint2*)Dst;
        uint2* go = (uint2*)(h2s + (size_t)vb * HID);
        go[t] = ds2[t];
    }
}

// ---------------- per-node edge accumulate for layer 2 ----------------
// sx: lane i holds epack4[rs+i] (plain src).  Broadcast h2s byte-offset per edge
// via readlane; gathers are per-lane vector loads (vmcnt, 8-deep in flight).
__device__ __forceinline__ float agg2_node(const int* __restrict__ epack4, int sx,
                                           int rs, int re, int lane, int lane2,
                                           const __half* __restrict__ h2s) {
    float acc = 0.0f;
    int p = rs;
    for (;;) {
        int avail = re - p;
        int cnt = avail > 64 ? 64 : avail;
        int vo = sx << 7;                  // src*128 byte offset
        int j = 0;
        for (; j + 8 <= cnt; j += 8) {
            float g[8];
#pragma unroll
            for (int i = 0; i < 8; ++i) {
                int off = __builtin_amdgcn_readlane(vo, j + i);
                g[i] = __half2float(*(const __half*)((const char*)h2s + (off + lane2)));
            }
#pragma unroll
            for (int i = 0; i < 8; ++i) acc += g[i];
        }
        if (j < cnt) {
#pragma unroll
            for (int i = 0; i < 8; ++i) {
                int jj = j + i;
                int off = __builtin_amdgcn_readlane(vo, jj & 63);
                float gv = __half2float(*(const __half*)((const char*)h2s + (off + lane2)));
                acc += (jj < cnt) ? gv : 0.0f;
            }
        }
        p += 64;
        if (p >= re) break;
        int idx = p + lane;
        idx = idx < N_EDGES ? idx : N_EDGES - 1;
        sx = epack4[idx];
    }
    return acc;
}

// ---------------- layer-2 aggregate + pool: 4 nodes/wave, run-merged atomics ----------------
__global__ __launch_bounds__(256, 8) void agg2_pool_kernel(
    const int* __restrict__ epack4, const int* __restrict__ rowptr,
    const __half* __restrict__ h2s, const float* __restrict__ dis,
    const float* __restrict__ b2, const int* __restrict__ batch,
    float* __restrict__ pooled) {
    int t = threadIdx.x, lane = t & 63, w = t >> 6;
    int lane2 = lane * 2;
    int v0 = (blockIdx.x * 4 + w) * 4;   // grid 6250

    int r0 = __builtin_amdgcn_readfirstlane(rowptr[v0]);
    int r1 = __builtin_amdgcn_readfirstlane(rowptr[v0 + 1]);
    int r2 = __builtin_amdgcn_readfirstlane(rowptr[v0 + 2]);
    int r3 = __builtin_amdgcn_readfirstlane(rowptr[v0 + 3]);
    int r4 = __builtin_amdgcn_readfirstlane(rowptr[v0 + 4]);

    int ia = r0 + lane; ia = ia < N_EDGES ? ia : N_EDGES - 1;
    int ib = r1 + lane; ib = ib < N_EDGES ? ib : N_EDGES - 1;
    int ic = r2 + lane; ic = ic < N_EDGES ? ic : N_EDGES - 1;
    int id = r3 + lane; id = id < N_EDGES ? id : N_EDGES - 1;
    int sa = epack4[ia];
    int sb = epack4[ib];
    int sc = epack4[ic];
    int sd = epack4[id];

    float bv = b2[lane];
    float acc0 = agg2_node(epack4, sa, r0, r1, lane, lane2, h2s);
    float acc1 = agg2_node(epack4, sb, r1, r2, lane, lane2, h2s);
    float acc2 = agg2_node(epack4, sc, r2, r3, lane, lane2, h2s);
    float acc3 = agg2_node(epack4, sd, r3, r4, lane, lane2, h2s);

#define AGG2_VAL(V, ACC, OUT)                                                  \
    {                                                                          \
        float dv = dis[V];                                                     \
        float self = __half2float(h2s[(size_t)(V) * HID + lane]);              \
        float val = dv * ((ACC) + self) + bv;                                  \
        OUT = val > 0.0f ? val : 0.0f;                                         \
    }
    float val0, val1, val2, val3;
    AGG2_VAL(v0, acc0, val0)
    AGG2_VAL(v0 + 1, acc1, val1)
    AGG2_VAL(v0 + 2, acc2, val2)
    AGG2_VAL(v0 + 3, acc3, val3)
#undef AGG2_VAL

    int g0 = __builtin_amdgcn_readfirstlane(batch[v0]);
    int g1 = __builtin_amdgcn_readfirstlane(batch[v0 + 1]);
    int g2 = __builtin_amdgcn_readfirstlane(batch[v0 + 2]);
    int g3 = __builtin_amdgcn_readfirstlane(batch[v0 + 3]);
    // batch is sorted: merge same-graph contributions into one atomic per run
    float s = val0; int g = g0;
    if (g1 == g) { s += val1; } else { unsafeAtomicAdd(&pooled[g * HID + lane], s); g = g1; s = val1; }
    if (g2 == g) { s += val2; } else { unsafeAtomicAdd(&pooled[g * HID + lane], s); g = g2; s = val2; }
    if (g3 == g) { s += val3; } else { unsafeAtomicAdd(&pooled[g * HID + lane], s); g = g3; s = val3; }
    unsafeAtomicAdd(&pooled[g * HID + lane], s);
}

// ---------------- logits ----------------
__global__ __launch_bounds__(64) void logits_kernel(
    const float* __restrict__ pooled, const int* __restrict__ gstart,
    const float* __restrict__ Wl, const float* __restrict__ bl,
    float* __restrict__ out) {
    __shared__ float row[HID];
    int g = blockIdx.x, t = threadIdx.x;
    int c = gstart[g + 1] - gstart[g]; if (c < 1) c = 1;
    row[t] = pooled[g * HID + t] / (float)c;
    __syncthreads();
    if (t < N_CLASSES) {
        float acc = bl[t];
#pragma unroll
        for (int k = 0; k < HID; ++k) acc = fmaf(row[k], Wl[k * N_CLASSES + t], acc);
        out[g * N_CLASSES + t] = acc;
    }
}

extern "C" void kernel_launch(void* const* d_in, const int* in_sizes, int n_in,
                              void* d_out, int out_size, void* d_ws, size_t ws_size,
                              hipStream_t stream) {
    const int*   shape_id = (const int*)d_in[0];
    const int*   color_id = (const int*)d_in[1];
    const int*   edge_idx = (const int*)d_in[2];
    const int*   batch    = (const int*)d_in[3];
    const float* st       = (const float*)d_in[4];
    const float* ct       = (const float*)d_in[5];
    const float* W1       = (const float*)d_in[6];
    const float* b1       = (const float*)d_in[7];
    const float* W2       = (const float*)d_in[8];
    const float* b2       = (const float*)d_in[9];
    const float* Wl       = (const float*)d_in[10];
    const float* bl       = (const float*)d_in[11];
    float* out = (float*)d_out;

    const int* src = edge_idx;
    const int* dst = edge_idx + N_EDGES;

    // workspace layout
    char* ws = (char*)d_ws;
    int*    combo   = (int*)   (ws + 0);            //   400,384 B
    float*  dis     = (float*) (ws + 400384);       //   400,384 B
    int*    gstart  = (int*)   (ws + 801792);       //     4,112 B
    int*    rowptr  = (int*)   (ws + 1201152);      //   400,384 B
    __half* TCh     = (__half*)(ws + 1603584);      //    19,968 B
    float*  pooled  = (float*) (ws + 1623552);      //   262,144 B
    int*    gcur    = (int*)   (ws + 1889792);      //     1,024 B
    int*    epack4  = (int*)   (ws + 1890816);      //  6,400,000 B (4B/edge, plain src)
    int*    gbin    = (int*)   (ws + 14690816);     //  7,340,032 B (packed single plane)
    __half* h2s     = (__half*)(ws + 29370880);     // 12,800,000 B (total ~42.2 MB)

    // 1. combo + batch boundaries + TC table + pooled/gcur zeroing (fused)
    prep_kernel<<<SCAN_BLOCKS, 256, 0, stream>>>(shape_id, color_id, batch, combo, gstart,
                                                 st, ct, W1, TCh, pooled, gcur);

    // 2. bin edges by dst-bucket (packed single plane, vectorized loads)
    binA_kernel<<<(N_EDGES + EPB - 1) / EPB, 512, 0, stream>>>(src, dst, gcur, gbin);

    // 3. merged: degrees + dis + rowptr + CSR scatter (one 6.4MB global read)
    bucket_scatter_kernel<<<NBUCK, 1024, 0, stream>>>(gbin, gcur, dis, rowptr, epack4);

    // 4. fused layer-1 aggregate + MFMA mm2 -> h2s (16 nodes/block)
    agg1_mm2_kernel<<<6250, 256, 0, stream>>>(epack4, rowptr, combo, dis, TCh, W2, b1, h2s);

    // 5. layer-2 aggregate + pool (8 waves/EU, plain-src edge reads)
    agg2_pool_kernel<<<6250, 256, 0, stream>>>(epack4, rowptr, h2s, dis, b2, batch, pooled);

    // 6. logits (counts from gstart boundaries)
    logits_kernel<<<N_GRAPHS, 64, 0, stream>>>(pooled, gstart, Wl, bl, out);
}

// Round 11
// 179.519 us; speedup vs baseline: 1.6417x; 1.0355x over previous
//
#include <hip/hip_runtime.h>
#include <hip/hip_bf16.h>
#include <hip/hip_fp16.h>

#define N_NODES   100000
#define N_EDGES   1600000
#define N_GRAPHS  1024
#define EMB       32
#define HID       64
#define N_CLASSES 10
#define SCAN_BLOCKS 391   // ceil(100000/256)
#define NCOMBO 153        // 17 shape ids x 9 color ids
#define BUCK_NODES 448    // nodes per dst-bucket
#define NBUCK 224         // ceil(100000/448)
#define BIN_CAP 8192      // per-bucket staging capacity (mean 7143, +12 sigma)
#define EPB 4096          // edges per binA block
#define PBCAP 11328       // padded per-bucket epack capacity (8192 + 448*7)
#define SENTINEL N_NODES  // pad src: dis=0, combo=0 (TC row 0 is all-zero), h2s row zeroed

typedef _Float16 f16x8 __attribute__((ext_vector_type(8)));
typedef float f32x4 __attribute__((ext_vector_type(4)));

// ---------------- prep: combo[v] + batch boundaries + TC table + buffer zeroing ----------------
__global__ __launch_bounds__(256) void prep_kernel(
    const int* __restrict__ sid, const int* __restrict__ cid,
    const int* __restrict__ batch, int* __restrict__ combo, int* __restrict__ gstart,
    const float* __restrict__ st, const float* __restrict__ ct,
    const float* __restrict__ W1, __half* __restrict__ TCh,
    float* __restrict__ pooled, int* __restrict__ gcur, __half* __restrict__ h2s) {
    int t = threadIdx.x;
    int v = blockIdx.x * 256 + t;
    if (v < N_GRAPHS * HID) pooled[v] = 0.0f;
    if (blockIdx.x == 0) {
        if (t < NBUCK) gcur[t] = 0;
        if (t == 0) combo[N_NODES] = 0;                 // sentinel combo -> TC row 0 (zeros)
        if (t < 32) ((float*)(h2s + (size_t)N_NODES * HID))[t] = 0.0f;  // sentinel h2s row
    }
    if (v < N_NODES) {
        combo[v] = sid[v] * 9 + cid[v];
        int b = batch[v];
        int bp = (v == 0) ? -1 : batch[v - 1];
        for (int g = bp + 1; g <= b; ++g) gstart[g] = v;      // boundary (usually 0 iters)
        if (v == N_NODES - 1) {
            for (int g = b + 1; g <= N_GRAPHS; ++g) gstart[g] = N_NODES;
        }
    }
    // TC table: TCh[s*9+c][j] = (st[s]@W1)[j] + (ct[c]@W1)[j]  (fp16)
    if (blockIdx.x < NCOMBO && t >= 64 && t < 128) {
        int r = blockIdx.x, j = t - 64;
        int s = r / 9, c = r % 9;
        float acc = 0.0f;
        if (s != 0) {
#pragma unroll
            for (int k = 0; k < EMB; ++k) acc = fmaf(st[s * EMB + k], W1[k * HID + j], acc);
        }
        if (c != 0) {
#pragma unroll
            for (int k = 0; k < EMB; ++k) acc = fmaf(ct[c * EMB + k], W1[k * HID + j], acc);
        }
        TCh[r * HID + j] = __float2half_rn(acc);
    }
}

// ---------------- binA: block-local counting sort by dst-bucket, packed single-plane flush ----------------
// gbin[e] = src | (local_dst << 17)   [src: 17b, local dst within bucket: 9b]
__global__ __launch_bounds__(512) void binA_kernel(
    const int* __restrict__ src, const int* __restrict__ dst,
    int* __restrict__ gcur, int* __restrict__ gbin) {
    __shared__ int2 stg[EPB];            // 32 KB
    __shared__ int hist[NBUCK];
    __shared__ int base[NBUCK + 1];
    __shared__ int gstart[NBUCK];
    __shared__ int scanbuf[256];
    int t = threadIdx.x;
    int e0 = blockIdx.x * EPB;
    for (int i = t; i < NBUCK; i += 512) hist[i] = 0;
    __syncthreads();

    int2 myq[8];
    int mybo[8];
    if (e0 + EPB <= N_EDGES) {
        int eb = e0 + t * 8;
        int4 sa4 = *(const int4*)&src[eb];
        int4 sb4 = *(const int4*)&src[eb + 4];
        int4 da4 = *(const int4*)&dst[eb];
        int4 db4 = *(const int4*)&dst[eb + 4];
        int ss[8] = {sa4.x, sa4.y, sa4.z, sa4.w, sb4.x, sb4.y, sb4.z, sb4.w};
        int dd[8] = {da4.x, da4.y, da4.z, da4.w, db4.x, db4.y, db4.z, db4.w};
#pragma unroll
        for (int i = 0; i < 8; ++i) {
            unsigned b = (unsigned)dd[i] / BUCK_NODES;
            int off = atomicAdd(&hist[b], 1);
            myq[i].x = ss[i];
            myq[i].y = dd[i];
            mybo[i] = (int)(b << 16) | off;
        }
    } else {
#pragma unroll
        for (int i = 0; i < 8; ++i) {
            int e = e0 + t * 8 + i;
            if (e < N_EDGES) {
                int d = dst[e];
                unsigned b = (unsigned)d / BUCK_NODES;
                int off = atomicAdd(&hist[b], 1);
                myq[i].x = src[e];
                myq[i].y = d;
                mybo[i] = (int)(b << 16) | off;
            } else {
                mybo[i] = -1;
            }
        }
    }
    __syncthreads();

    int h = (t < NBUCK) ? hist[t] : 0;
    if (t < 256) scanbuf[t] = h;
    __syncthreads();
#pragma unroll
    for (int off = 1; off < 256; off <<= 1) {
        int x = (t < 256 && t >= off) ? scanbuf[t - off] : 0;
        __syncthreads();
        if (t < 256) scanbuf[t] += x;
        __syncthreads();
    }
    if (t < NBUCK) base[t] = scanbuf[t] - h;
    if (t == 0) base[NBUCK] = scanbuf[255];
    __syncthreads();
#pragma unroll
    for (int i = 0; i < 8; ++i) {
        if (mybo[i] >= 0) {
            int b = mybo[i] >> 16, off = mybo[i] & 0xFFFF;
            stg[base[b] + off] = myq[i];
        }
    }
    if (t < NBUCK) {
        int n = hist[t];
        gstart[t] = n ? atomicAdd(&gcur[t], n) : 0;
    }
    __syncthreads();
    int total = base[NBUCK];
    for (int i = t; i < total; i += 512) {
        int2 q = stg[i];
        unsigned b = (unsigned)q.y / BUCK_NODES;
        int local = q.y - (int)b * BUCK_NODES;          // < 448, 9 bits
        gbin[(size_t)b * BIN_CAP + gstart[b] + (i - base[b])] = q.x | (local << 17);
    }
}

// ---------------- bucket_scatter: degrees + dis + packed rowptr + padded CSR scatter ----------------
// Bucket b owns epack region [b*PBCAP, b*PBCAP + padded_total).  Each node's row is
// padded to a multiple of 8 with SENTINEL (exact-zero contributions downstream).
// rowptr[v] = rp | (dp << 24)  [rp: 24b padded base, dp: padded degree <= 248]
__global__ __launch_bounds__(1024) void bucket_scatter_kernel(
    const int* __restrict__ gbin, const int* __restrict__ gcur,
    float* __restrict__ dis, int* __restrict__ rowptr, int* __restrict__ epack4) {
    __shared__ __align__(16) int pbin[BIN_CAP];   // 32 KB: staged packed plane
    __shared__ int ldeg[BUCK_NODES];              // degree count, then scatter cursors
    __shared__ int rbase[BUCK_NODES];             // per-node absolute padded base
    __shared__ int s[512];
    int b = blockIdx.x, t = threadIdx.x;
    for (int i = t; i < BUCK_NODES; i += 1024) ldeg[i] = 0;
    __syncthreads();
    int n = gcur[b];
    int nc = (n + 3) >> 2;
    // pass 1: stage packed plane + count true degrees (int4 stream)
    {
        const int4* my4 = (const int4*)(gbin + (size_t)b * BIN_CAP);
        for (int c = t; c < nc; c += 1024) {
            int4 p4 = my4[c];
            ((int4*)pbin)[c] = p4;
            int i0 = c * 4;
            if (i0 + 0 < n) atomicAdd(&ldeg[(unsigned)p4.x >> 17], 1);
            if (i0 + 1 < n) atomicAdd(&ldeg[(unsigned)p4.y >> 17], 1);
            if (i0 + 2 < n) atomicAdd(&ldeg[(unsigned)p4.z >> 17], 1);
            if (i0 + 3 < n) atomicAdd(&ldeg[(unsigned)p4.w >> 17], 1);
        }
    }
    __syncthreads();
    int d = (t < BUCK_NODES) ? ldeg[t] : 0;
    int v = b * BUCK_NODES + t;
    if (t < BUCK_NODES && v < N_NODES) dis[v] = rsqrtf(1.0f + (float)d);
    if (b == 0 && t == 0) dis[N_NODES] = 0.0f;    // sentinel weight = 0
    int dp = (d + 7) & ~7;                        // pad to multiple of 8
    if (dp > 248) dp = 248;                       // 8-bit pack bound (P ~ 0)
    if (t < 512) s[t] = dp;
    __syncthreads();
#pragma unroll
    for (int off = 1; off < 512; off <<= 1) {
        int x = (t < 512 && t >= off) ? s[t - off] : 0;
        __syncthreads();
        if (t < 512) s[t] += x;
        __syncthreads();
    }
    int rp = 0;
    if (t < 512) rp = b * PBCAP + s[t] - dp;
    if (t < BUCK_NODES) {
        rbase[t] = rp;
        if (v < N_NODES) rowptr[v] = rp | (dp << 24);
    }
    // reset cursors
    for (int i = t; i < BUCK_NODES; i += 1024) ldeg[i] = 0;
    __syncthreads();
    // pad-fill: thread t fills its own node's sentinel slots (<= 7)
    if (t < BUCK_NODES) {
        for (int k = d; k < dp; ++k) epack4[rp + k] = SENTINEL;
    }
    // pass 2: pure-LDS scatter (dense writes within bucket's padded region)
    for (int i = t; i < n; i += 1024) {
        int p = pbin[i];
        int local = (unsigned)p >> 17;
        int r = atomicAdd(&ldeg[local], 1);
        if (r < 248) epack4[rbase[local] + r] = p & 0x1FFFF;
    }
}

// ---------------- fused layer-1 aggregate + MFMA mm2 ----------------
// Block = 16 consecutive nodes; wave w owns nodes v0..v0+3 for aggregation.
// Rows are sentinel-padded to multiples of 8 -> NO per-edge masking.
// mm2: block-cooperative X(16x64,fp16) @ W2(64x64,fp16) via 2x mfma_f32_16x16x32_f16.
#define AGG_CHUNK(CQ, DQ, LBASE)                                               \
    _Pragma("unroll")                                                          \
    for (int i = 0; i < 8; ++i) {                                              \
        int off = __builtin_amdgcn_readlane((CQ), (LBASE) + i);                \
        int wb  = __builtin_amdgcn_readlane(__float_as_int(DQ), (LBASE) + i);  \
        __half tv = *(const __half*)((const char*)TCs + (off + lane2));        \
        acc = fmaf(__int_as_float(wb), __half2float(tv), acc);                 \
    }

#define AGG_NODE(N, RP, DEG, DV, CO)                                           \
    {                                                                          \
        int deg = (DEG);                                                       \
        int cnt = deg > 32 ? 32 : deg;                                         \
        float acc = 0.0f;                                                      \
        if (cnt > 0)  { AGG_CHUNK(cq1, dq1, (N)*16) }                          \
        if (cnt > 8)  { AGG_CHUNK(cq1, dq1, (N)*16 + 8) }                      \
        if (cnt > 16) { AGG_CHUNK(cq2, dq2, (N)*16) }                          \
        if (cnt > 24) { AGG_CHUNK(cq2, dq2, (N)*16 + 8) }                      \
        if (deg > 32) {                                                        \
            for (int e = (RP) + 32; e < (RP) + deg; ++e) {                     \
                int qx = epack4[e] & 0x1FFFF;                                  \
                float dw = dis[qx];                                            \
                __half tv = *(const __half*)((const char*)TCs +                \
                                             ((combo[qx] << 7) + lane2));      \
                acc = fmaf(dw, __half2float(tv), acc);                         \
            }                                                                  \
        }                                                                      \
        __half hv = *(const __half*)((const char*)TCs + ((CO) + lane2));       \
        float val = (DV) * fmaf(__half2float(hv), (DV), acc) + bias;           \
        val = val > 0.0f ? val : 0.0f;                                         \
        xsA[w * 4 + (N)][lane] = __float2half_rn(val * (DV));                  \
    }

__global__ __launch_bounds__(256, 8) void agg1_mm2_kernel(
    const int* __restrict__ epack4, const int* __restrict__ rowptr,
    const int* __restrict__ combo, const float* __restrict__ dis,
    const __half* __restrict__ TCh, const float* __restrict__ W2,
    const float* __restrict__ b1, __half* __restrict__ h2s) {
    __shared__ __align__(16) __half TCs[NCOMBO * HID];  // 19,584 B
    __shared__ __align__(16) __half xsA[16][72];        //  2,304 B (reused as Dst)
    int t = threadIdx.x;
    int lane = t & 63, w = t >> 6;
    int lane2 = lane * 2;
    int vb = blockIdx.x * 16;
    int v0 = vb + w * 4;

    // per-lane sliced edge prefetch (longest latency chain - issue first)
    int sub = lane >> 4, sl = lane & 15;
    int rb = rowptr[v0 + sub] & 0xFFFFFF;
    int q1x = epack4[rb + sl] & 0x1FFFF;        // node sub, slots 0..15
    int q2x = epack4[rb + 16 + sl] & 0x1FFFF;   // node sub, slots 16..31 (over-read ok, in-ws)
    float dq1 = dis[q1x];                       // dependent gathers, L2-resident
    float dq2 = dis[q2x];
    int cq1 = combo[q1x] << 7;                  // TC byte offset
    int cq2 = combo[q2x] << 7;

    // packed row pointers: rp | (padded_deg << 24)
    int r0p = __builtin_amdgcn_readfirstlane(rowptr[v0]);
    int r1p = __builtin_amdgcn_readfirstlane(rowptr[v0 + 1]);
    int r2p = __builtin_amdgcn_readfirstlane(rowptr[v0 + 2]);
    int r3p = __builtin_amdgcn_readfirstlane(rowptr[v0 + 3]);
    int r0 = r0p & 0xFFFFFF, g0 = (int)((unsigned)r0p >> 24);
    int r1 = r1p & 0xFFFFFF, g1 = (int)((unsigned)r1p >> 24);
    int r2 = r2p & 0xFFFFFF, g2 = (int)((unsigned)r2p >> 24);
    int r3 = r3p & 0xFFFFFF, g3 = (int)((unsigned)r3p >> 24);

    // per-node epilogue scalars (issue early)
    float d0 = dis[v0], d1 = dis[v0 + 1], d2 = dis[v0 + 2], d3 = dis[v0 + 3];
    int o0 = combo[v0] << 7, o1 = combo[v0 + 1] << 7;
    int o2 = combo[v0 + 2] << 7, o3 = combo[v0 + 3] << 7;
    float bias = b1[lane];

    // B fragments of W2 for this wave's 16 output cols (built once, from global)
    f16x8 bf0, bf1;
    {
        int colw = (w << 4) + (lane & 15);
        int kb = (lane >> 4) * 8;
#pragma unroll
        for (int i = 0; i < 8; ++i) {
            bf0[i] = (_Float16)W2[(kb + i) * HID + colw];
            bf1[i] = (_Float16)W2[(32 + kb + i) * HID + colw];
        }
    }

    // stage TC table to LDS
    {
        const int4* s4 = (const int4*)TCh;
        int4* dd4 = (int4*)TCs;
        for (int i = t; i < NCOMBO * HID * 2 / 16; i += 256) dd4[i] = s4[i];
    }
    __syncthreads();   // also drains the edge + dis + combo prefetch

    AGG_NODE(0, r0, g0, d0, o0)
    AGG_NODE(1, r1, g1, d1, o1)
    AGG_NODE(2, r2, g2, d2, o2)
    AGG_NODE(3, r3, g3, d3, o3)

    __syncthreads();   // all 16 rows of xsA ready

    // A fragments: row = lane&15 (node), k = (lane>>4)*8 + i  (+32 for 2nd MFMA)
    const __half* xa = &xsA[lane & 15][0];
    f16x8 a0 = *(const f16x8*)(xa + (lane >> 4) * 8);
    f16x8 a1 = *(const f16x8*)(xa + 32 + (lane >> 4) * 8);
    __syncthreads();   // a-frags in regs; safe to reuse xsA as Dst
    f32x4 dacc = {0.0f, 0.0f, 0.0f, 0.0f};
    dacc = __builtin_amdgcn_mfma_f32_16x16x32_f16(a0, bf0, dacc, 0, 0, 0);
    dacc = __builtin_amdgcn_mfma_f32_16x16x32_f16(a1, bf1, dacc, 0, 0, 0);

    // D: col = lane&15 (within wave's 16-col block), row = (lane>>4)*4 + i (node)
    __half* Dst = (__half*)xsA;   // flat [16*64] reuse
    {
        int colg = (w << 4) + (lane & 15);
#pragma unroll
        for (int i = 0; i < 4; ++i)
            Dst[((lane >> 4) * 4 + i) * 64 + colg] = __float2half_rn(dacc[i]);
    }
    __syncthreads();

    // coalesced block store: 16 nodes x 64 feats fp16 = 2048 B contiguous
    {
        const uint2* ds2 = (const uint2*)Dst;
        uint2* go = (uint2*)(h2s + (size_t)vb * HID);
        go[t] = ds2[t];
    }
}

// ---------------- per-node edge accumulate for layer 2 ----------------
// Rows sentinel-padded to multiples of 8; sentinel h2s row is zeroed -> unmasked chunks.
__device__ __forceinline__ float agg2_node(const int* __restrict__ epack4, int sx,
                                           int rs, int deg, int lane, int lane2,
                                           const __half* __restrict__ h2s) {
    float acc = 0.0f;
    int p = rs;
    int re = rs + deg;
    for (;;) {
        int avail = re - p;
        int cnt = avail > 64 ? 64 : avail;   // multiple of 8
        int vo = sx << 7;                    // src*128 byte offset
        for (int j = 0; j + 8 <= cnt; j += 8) {
            float g[8];
#pragma unroll
            for (int i = 0; i < 8; ++i) {
                int off = __builtin_amdgcn_readlane(vo, j + i);
                g[i] = __half2float(*(const __half*)((const char*)h2s + (off + lane2)));
            }
#pragma unroll
            for (int i = 0; i < 8; ++i) acc += g[i];
        }
        p += 64;
        if (p >= re) break;
        sx = epack4[p + lane];
    }
    return acc;
}

// ---------------- layer-2 aggregate + pool: 4 nodes/wave, run-merged atomics ----------------
__global__ __launch_bounds__(256, 8) void agg2_pool_kernel(
    const int* __restrict__ epack4, const int* __restrict__ rowptr,
    const __half* __restrict__ h2s, const float* __restrict__ dis,
    const float* __restrict__ b2, const int* __restrict__ batch,
    float* __restrict__ pooled) {
    int t = threadIdx.x, lane = t & 63, w = t >> 6;
    int lane2 = lane * 2;
    int v0 = (blockIdx.x * 4 + w) * 4;   // grid 6250

    int r0p = __builtin_amdgcn_readfirstlane(rowptr[v0]);
    int r1p = __builtin_amdgcn_readfirstlane(rowptr[v0 + 1]);
    int r2p = __builtin_amdgcn_readfirstlane(rowptr[v0 + 2]);
    int r3p = __builtin_amdgcn_readfirstlane(rowptr[v0 + 3]);
    int r0 = r0p & 0xFFFFFF, dp0 = (int)((unsigned)r0p >> 24);
    int r1 = r1p & 0xFFFFFF, dp1 = (int)((unsigned)r1p >> 24);
    int r2 = r2p & 0xFFFFFF, dp2 = (int)((unsigned)r2p >> 24);
    int r3 = r3p & 0xFFFFFF, dp3 = (int)((unsigned)r3p >> 24);

    int sa = epack4[r0 + lane];
    int sb = epack4[r1 + lane];
    int sc = epack4[r2 + lane];
    int sd = epack4[r3 + lane];

    float bv = b2[lane];
    float acc0 = agg2_node(epack4, sa, r0, dp0, lane, lane2, h2s);
    float acc1 = agg2_node(epack4, sb, r1, dp1, lane, lane2, h2s);
    float acc2 = agg2_node(epack4, sc, r2, dp2, lane, lane2, h2s);
    float acc3 = agg2_node(epack4, sd, r3, dp3, lane, lane2, h2s);

#define AGG2_VAL(V, ACC, OUT)                                                  \
    {                                                                          \
        float dv = dis[V];                                                     \
        float self = __half2float(h2s[(size_t)(V) * HID + lane]);              \
        float val = dv * ((ACC) + self) + bv;                                  \
        OUT = val > 0.0f ? val : 0.0f;                                         \
    }
    float val0, val1, val2, val3;
    AGG2_VAL(v0, acc0, val0)
    AGG2_VAL(v0 + 1, acc1, val1)
    AGG2_VAL(v0 + 2, acc2, val2)
    AGG2_VAL(v0 + 3, acc3, val3)
#undef AGG2_VAL

    int g0 = __builtin_amdgcn_readfirstlane(batch[v0]);
    int g1 = __builtin_amdgcn_readfirstlane(batch[v0 + 1]);
    int g2 = __builtin_amdgcn_readfirstlane(batch[v0 + 2]);
    int g3 = __builtin_amdgcn_readfirstlane(batch[v0 + 3]);
    // batch is sorted: merge same-graph contributions into one atomic per run
    float s = val0; int g = g0;
    if (g1 == g) { s += val1; } else { unsafeAtomicAdd(&pooled[g * HID + lane], s); g = g1; s = val1; }
    if (g2 == g) { s += val2; } else { unsafeAtomicAdd(&pooled[g * HID + lane], s); g = g2; s = val2; }
    if (g3 == g) { s += val3; } else { unsafeAtomicAdd(&pooled[g * HID + lane], s); g = g3; s = val3; }
    unsafeAtomicAdd(&pooled[g * HID + lane], s);
}

// ---------------- logits ----------------
__global__ __launch_bounds__(64) void logits_kernel(
    const float* __restrict__ pooled, const int* __restrict__ gstart,
    const float* __restrict__ Wl, const float* __restrict__ bl,
    float* __restrict__ out) {
    __shared__ float row[HID];
    int g = blockIdx.x, t = threadIdx.x;
    int c = gstart[g + 1] - gstart[g]; if (c < 1) c = 1;
    row[t] = pooled[g * HID + t] / (float)c;
    __syncthreads();
    if (t < N_CLASSES) {
        float acc = bl[t];
#pragma unroll
        for (int k = 0; k < HID; ++k) acc = fmaf(row[k], Wl[k * N_CLASSES + t], acc);
        out[g * N_CLASSES + t] = acc;
    }
}

extern "C" void kernel_launch(void* const* d_in, const int* in_sizes, int n_in,
                              void* d_out, int out_size, void* d_ws, size_t ws_size,
                              hipStream_t stream) {
    const int*   shape_id = (const int*)d_in[0];
    const int*   color_id = (const int*)d_in[1];
    const int*   edge_idx = (const int*)d_in[2];
    const int*   batch    = (const int*)d_in[3];
    const float* st       = (const float*)d_in[4];
    const float* ct       = (const float*)d_in[5];
    const float* W1       = (const float*)d_in[6];
    const float* b1       = (const float*)d_in[7];
    const float* W2       = (const float*)d_in[8];
    const float* b2       = (const float*)d_in[9];
    const float* Wl       = (const float*)d_in[10];
    const float* bl       = (const float*)d_in[11];
    float* out = (float*)d_out;

    const int* src = edge_idx;
    const int* dst = edge_idx + N_EDGES;

    // workspace layout
    char* ws = (char*)d_ws;
    int*    combo   = (int*)   (ws + 0);            //   400,384 B (index N_NODES valid)
    float*  dis     = (float*) (ws + 400384);       //   400,384 B (index N_NODES valid)
    int*    gstart  = (int*)   (ws + 801792);       //     4,112 B
    int*    rowptr  = (int*)   (ws + 1201152);      //   400,384 B (packed rp|dp<<24)
    __half* TCh     = (__half*)(ws + 1603584);      //    19,968 B
    float*  pooled  = (float*) (ws + 1623552);      //   262,144 B
    int*    gcur    = (int*)   (ws + 1889792);      //     1,024 B
    int*    epack4  = (int*)   (ws + 1890816);      // 10,149,888 B (224 x 11328 x 4B padded)
    int*    gbin    = (int*)   (ws + 14690816);     //  7,340,032 B (packed single plane)
    __half* h2s     = (__half*)(ws + 29370880);     // 12,800,128 B (+ sentinel row)

    // 1. combo + batch boundaries + TC table + pooled/gcur/sentinel zeroing (fused)
    prep_kernel<<<SCAN_BLOCKS, 256, 0, stream>>>(shape_id, color_id, batch, combo, gstart,
                                                 st, ct, W1, TCh, pooled, gcur, h2s);

    // 2. bin edges by dst-bucket (packed single plane, vectorized loads)
    binA_kernel<<<(N_EDGES + EPB - 1) / EPB, 512, 0, stream>>>(src, dst, gcur, gbin);

    // 3. merged: degrees + dis + packed rowptr + sentinel-padded CSR scatter
    bucket_scatter_kernel<<<NBUCK, 1024, 0, stream>>>(gbin, gcur, dis, rowptr, epack4);

    // 4. fused layer-1 aggregate + MFMA mm2 -> h2s (maskless chunks, LDS union)
    agg1_mm2_kernel<<<6250, 256, 0, stream>>>(epack4, rowptr, combo, dis, TCh, W2, b1, h2s);

    // 5. layer-2 aggregate + pool (maskless chunks)
    agg2_pool_kernel<<<6250, 256, 0, stream>>>(epack4, rowptr, h2s, dis, b2, batch, pooled);

    // 6. logits (counts from gstart boundaries)
    logits_kernel<<<N_GRAPHS, 64, 0, stream>>>(pooled, gstart, Wl, bl, out);
}

// Round 12
// 176.130 us; speedup vs baseline: 1.6733x; 1.0192x over previous
//
#include <hip/hip_runtime.h>
#include <hip/hip_bf16.h>
#include <hip/hip_fp16.h>

#define N_NODES   100000
#define N_EDGES   1600000
#define N_GRAPHS  1024
#define EMB       32
#define HID       64
#define N_CLASSES 10
#define SCAN_BLOCKS 391   // ceil(100000/256)
#define NCOMBO 153        // 17 shape ids x 9 color ids
#define BUCK_NODES 448    // nodes per dst-bucket
#define NBUCK 224         // ceil(100000/448)
#define BIN_CAP 8192      // per-bucket staging capacity (mean 7143, +12 sigma)
#define EPB 4096          // edges per binA block
#define PBCAP 11328       // padded per-bucket epack capacity (8192 + 448*7)
#define SENTINEL N_NODES  // pad src: dis=0, combo=0 (TC row 0 is all-zero), h2s row zeroed
#define NTILES 6250       // 100000 / 16
#define AGG_GRID 3125     // persistent agg1 blocks: exactly 2 tiles each

typedef _Float16 f16x8 __attribute__((ext_vector_type(8)));
typedef float f32x4 __attribute__((ext_vector_type(4)));

// ---------------- prep: combo[v] + batch boundaries + TC table + buffer zeroing ----------------
__global__ __launch_bounds__(256) void prep_kernel(
    const int* __restrict__ sid, const int* __restrict__ cid,
    const int* __restrict__ batch, int* __restrict__ combo, int* __restrict__ gstart,
    const float* __restrict__ st, const float* __restrict__ ct,
    const float* __restrict__ W1, __half* __restrict__ TCh,
    float* __restrict__ pooled, int* __restrict__ gcur, __half* __restrict__ h2s) {
    int t = threadIdx.x;
    int v = blockIdx.x * 256 + t;
    if (v < N_GRAPHS * HID) pooled[v] = 0.0f;
    if (blockIdx.x == 0) {
        if (t < NBUCK) gcur[t] = 0;
        if (t == 0) combo[N_NODES] = 0;                 // sentinel combo -> TC row 0 (zeros)
        if (t < 32) ((float*)(h2s + (size_t)N_NODES * HID))[t] = 0.0f;  // sentinel h2s row
    }
    if (v < N_NODES) {
        combo[v] = sid[v] * 9 + cid[v];
        int b = batch[v];
        int bp = (v == 0) ? -1 : batch[v - 1];
        for (int g = bp + 1; g <= b; ++g) gstart[g] = v;      // boundary (usually 0 iters)
        if (v == N_NODES - 1) {
            for (int g = b + 1; g <= N_GRAPHS; ++g) gstart[g] = N_NODES;
        }
    }
    // TC table: TCh[s*9+c][j] = (st[s]@W1)[j] + (ct[c]@W1)[j]  (fp16)
    if (blockIdx.x < NCOMBO && t >= 64 && t < 128) {
        int r = blockIdx.x, j = t - 64;
        int s = r / 9, c = r % 9;
        float acc = 0.0f;
        if (s != 0) {
#pragma unroll
            for (int k = 0; k < EMB; ++k) acc = fmaf(st[s * EMB + k], W1[k * HID + j], acc);
        }
        if (c != 0) {
#pragma unroll
            for (int k = 0; k < EMB; ++k) acc = fmaf(ct[c * EMB + k], W1[k * HID + j], acc);
        }
        TCh[r * HID + j] = __float2half_rn(acc);
    }
}

// ---------------- binA: block-local counting sort by dst-bucket, packed single-plane flush ----------------
// gbin[e] = src | (local_dst << 17)   [src: 17b, local dst within bucket: 9b]
__global__ __launch_bounds__(512) void binA_kernel(
    const int* __restrict__ src, const int* __restrict__ dst,
    int* __restrict__ gcur, int* __restrict__ gbin) {
    __shared__ int2 stg[EPB];            // 32 KB
    __shared__ int hist[NBUCK];
    __shared__ int base[NBUCK + 1];
    __shared__ int gstart[NBUCK];
    __shared__ int scanbuf[256];
    int t = threadIdx.x;
    int e0 = blockIdx.x * EPB;
    for (int i = t; i < NBUCK; i += 512) hist[i] = 0;
    __syncthreads();

    int2 myq[8];
    int mybo[8];
    if (e0 + EPB <= N_EDGES) {
        int eb = e0 + t * 8;
        int4 sa4 = *(const int4*)&src[eb];
        int4 sb4 = *(const int4*)&src[eb + 4];
        int4 da4 = *(const int4*)&dst[eb];
        int4 db4 = *(const int4*)&dst[eb + 4];
        int ss[8] = {sa4.x, sa4.y, sa4.z, sa4.w, sb4.x, sb4.y, sb4.z, sb4.w};
        int dd[8] = {da4.x, da4.y, da4.z, da4.w, db4.x, db4.y, db4.z, db4.w};
#pragma unroll
        for (int i = 0; i < 8; ++i) {
            unsigned b = (unsigned)dd[i] / BUCK_NODES;
            int off = atomicAdd(&hist[b], 1);
            myq[i].x = ss[i];
            myq[i].y = dd[i];
            mybo[i] = (int)(b << 16) | off;
        }
    } else {
#pragma unroll
        for (int i = 0; i < 8; ++i) {
            int e = e0 + t * 8 + i;
            if (e < N_EDGES) {
                int d = dst[e];
                unsigned b = (unsigned)d / BUCK_NODES;
                int off = atomicAdd(&hist[b], 1);
                myq[i].x = src[e];
                myq[i].y = d;
                mybo[i] = (int)(b << 16) | off;
            } else {
                mybo[i] = -1;
            }
        }
    }
    __syncthreads();

    int h = (t < NBUCK) ? hist[t] : 0;
    if (t < 256) scanbuf[t] = h;
    __syncthreads();
#pragma unroll
    for (int off = 1; off < 256; off <<= 1) {
        int x = (t < 256 && t >= off) ? scanbuf[t - off] : 0;
        __syncthreads();
        if (t < 256) scanbuf[t] += x;
        __syncthreads();
    }
    if (t < NBUCK) base[t] = scanbuf[t] - h;
    if (t == 0) base[NBUCK] = scanbuf[255];
    __syncthreads();
#pragma unroll
    for (int i = 0; i < 8; ++i) {
        if (mybo[i] >= 0) {
            int b = mybo[i] >> 16, off = mybo[i] & 0xFFFF;
            stg[base[b] + off] = myq[i];
        }
    }
    if (t < NBUCK) {
        int n = hist[t];
        gstart[t] = n ? atomicAdd(&gcur[t], n) : 0;
    }
    __syncthreads();
    int total = base[NBUCK];
    for (int i = t; i < total; i += 512) {
        int2 q = stg[i];
        unsigned b = (unsigned)q.y / BUCK_NODES;
        int local = q.y - (int)b * BUCK_NODES;          // < 448, 9 bits
        gbin[(size_t)b * BIN_CAP + gstart[b] + (i - base[b])] = q.x | (local << 17);
    }
}

// ---------------- bucket_scatter: degrees + dis + packed rowptr + padded CSR scatter ----------------
// rowptr[v] = rp | (dp << 24)  [rp: 24b padded base, dp: padded degree <= 248]
__global__ __launch_bounds__(1024) void bucket_scatter_kernel(
    const int* __restrict__ gbin, const int* __restrict__ gcur,
    float* __restrict__ dis, int* __restrict__ rowptr, int* __restrict__ epack4) {
    __shared__ __align__(16) int pbin[BIN_CAP];   // 32 KB: staged packed plane
    __shared__ int ldeg[BUCK_NODES];              // degree count, then scatter cursors
    __shared__ int rbase[BUCK_NODES];             // per-node absolute padded base
    __shared__ int s[512];
    int b = blockIdx.x, t = threadIdx.x;
    for (int i = t; i < BUCK_NODES; i += 1024) ldeg[i] = 0;
    __syncthreads();
    int n = gcur[b];
    int nc = (n + 3) >> 2;
    // pass 1: stage packed plane + count true degrees (int4 stream)
    {
        const int4* my4 = (const int4*)(gbin + (size_t)b * BIN_CAP);
        for (int c = t; c < nc; c += 1024) {
            int4 p4 = my4[c];
            ((int4*)pbin)[c] = p4;
            int i0 = c * 4;
            if (i0 + 0 < n) atomicAdd(&ldeg[(unsigned)p4.x >> 17], 1);
            if (i0 + 1 < n) atomicAdd(&ldeg[(unsigned)p4.y >> 17], 1);
            if (i0 + 2 < n) atomicAdd(&ldeg[(unsigned)p4.z >> 17], 1);
            if (i0 + 3 < n) atomicAdd(&ldeg[(unsigned)p4.w >> 17], 1);
        }
    }
    __syncthreads();
    int d = (t < BUCK_NODES) ? ldeg[t] : 0;
    int v = b * BUCK_NODES + t;
    if (t < BUCK_NODES && v < N_NODES) dis[v] = rsqrtf(1.0f + (float)d);
    if (b == 0 && t == 0) dis[N_NODES] = 0.0f;    // sentinel weight = 0
    int dp = (d + 7) & ~7;                        // pad to multiple of 8
    if (dp > 248) dp = 248;                       // 8-bit pack bound (P ~ 0)
    if (t < 512) s[t] = dp;
    __syncthreads();
#pragma unroll
    for (int off = 1; off < 512; off <<= 1) {
        int x = (t < 512 && t >= off) ? s[t - off] : 0;
        __syncthreads();
        if (t < 512) s[t] += x;
        __syncthreads();
    }
    int rp = 0;
    if (t < 512) rp = b * PBCAP + s[t] - dp;
    if (t < BUCK_NODES) {
        rbase[t] = rp;
        if (v < N_NODES) rowptr[v] = rp | (dp << 24);
    }
    // reset cursors
    for (int i = t; i < BUCK_NODES; i += 1024) ldeg[i] = 0;
    __syncthreads();
    // pad-fill: thread t fills its own node's sentinel slots (<= 7)
    if (t < BUCK_NODES) {
        for (int k = d; k < dp; ++k) epack4[rp + k] = SENTINEL;
    }
    // pass 2: pure-LDS scatter (dense writes within bucket's padded region)
    for (int i = t; i < n; i += 1024) {
        int p = pbin[i];
        int local = (unsigned)p >> 17;
        int r = atomicAdd(&ldeg[local], 1);
        if (r < 248) epack4[rbase[local] + r] = p & 0x1FFFF;
    }
}

// ---------------- fused layer-1 aggregate + MFMA mm2 (persistent, 2 tiles/block) ----------------
// Rows sentinel-padded to multiples of 8 -> NO per-edge masking.  TC staging and
// W2 fragments amortized over 2 tiles; tile-2's rowptr->epack->dis/combo prefetch
// chain is issued before tile-1's AGG phase (hidden under it).
#define AGG_CHUNK(CQ, DQ, LBASE)                                               \
    _Pragma("unroll")                                                          \
    for (int i = 0; i < 8; ++i) {                                              \
        int off = __builtin_amdgcn_readlane((CQ), (LBASE) + i);                \
        int wb  = __builtin_amdgcn_readlane(__float_as_int(DQ), (LBASE) + i);  \
        __half tv = *(const __half*)((const char*)TCs + (off + lane2));        \
        acc = fmaf(__int_as_float(wb), __half2float(tv), acc);                 \
    }

#define AGG_NODE(N, RP, DEG, DV, CO)                                           \
    {                                                                          \
        int deg = (DEG);                                                       \
        int cnt = deg > 32 ? 32 : deg;                                         \
        float acc = 0.0f;                                                      \
        if (cnt > 0)  { AGG_CHUNK(cq1, dq1, (N)*16) }                          \
        if (cnt > 8)  { AGG_CHUNK(cq1, dq1, (N)*16 + 8) }                      \
        if (cnt > 16) { AGG_CHUNK(cq2, dq2, (N)*16) }                          \
        if (cnt > 24) { AGG_CHUNK(cq2, dq2, (N)*16 + 8) }                      \
        if (deg > 32) {                                                        \
            for (int e = (RP) + 32; e < (RP) + deg; ++e) {                     \
                int qx = epack4[e] & 0x1FFFF;                                  \
                float dw = dis[qx];                                            \
                __half tv = *(const __half*)((const char*)TCs +                \
                                             ((combo[qx] << 7) + lane2));      \
                acc = fmaf(dw, __half2float(tv), acc);                         \
            }                                                                  \
        }                                                                      \
        __half hv = *(const __half*)((const char*)TCs + ((CO) + lane2));       \
        float val = (DV) * fmaf(__half2float(hv), (DV), acc) + bias;           \
        val = val > 0.0f ? val : 0.0f;                                         \
        xsA[w * 4 + (N)][lane] = __float2half_rn(val * (DV));                  \
    }

__global__ __launch_bounds__(256, 7) void agg1_mm2_kernel(
    const int* __restrict__ epack4, const int* __restrict__ rowptr,
    const int* __restrict__ combo, const float* __restrict__ dis,
    const __half* __restrict__ TCh, const float* __restrict__ W2,
    const float* __restrict__ b1, __half* __restrict__ h2s) {
    __shared__ __align__(16) __half TCs[NCOMBO * HID];  // 19,584 B
    __shared__ __align__(16) __half xsA[16][72];        //  2,304 B (reused as Dst)
    int t = threadIdx.x;
    int lane = t & 63, w = t >> 6;
    int lane2 = lane * 2;
    int sub = lane >> 4, sl = lane & 15;

    // ---- first-tile prefetch (hidden under TC staging) ----
    int tile = blockIdx.x;
    int v0 = tile * 16 + w * 4;
    {
        // issue the longest chain first
    }
    int rb = rowptr[v0 + sub] & 0xFFFFFF;
    int q1x = epack4[rb + sl] & 0x1FFFF;
    int q2x = epack4[rb + 16 + sl] & 0x1FFFF;
    float dq1 = dis[q1x], dq2 = dis[q2x];
    int cq1 = combo[q1x] << 7, cq2 = combo[q2x] << 7;
    int r0p = __builtin_amdgcn_readfirstlane(rowptr[v0]);
    int r1p = __builtin_amdgcn_readfirstlane(rowptr[v0 + 1]);
    int r2p = __builtin_amdgcn_readfirstlane(rowptr[v0 + 2]);
    int r3p = __builtin_amdgcn_readfirstlane(rowptr[v0 + 3]);
    float d0 = dis[v0], d1 = dis[v0 + 1], d2 = dis[v0 + 2], d3 = dis[v0 + 3];
    int o0 = combo[v0] << 7, o1 = combo[v0 + 1] << 7;
    int o2 = combo[v0 + 2] << 7, o3 = combo[v0 + 3] << 7;

    float bias = b1[lane];
    // B fragments of W2 (built once per block)
    f16x8 bf0, bf1;
    {
        int colw = (w << 4) + (lane & 15);
        int kb = (lane >> 4) * 8;
#pragma unroll
        for (int i = 0; i < 8; ++i) {
            bf0[i] = (_Float16)W2[(kb + i) * HID + colw];
            bf1[i] = (_Float16)W2[(32 + kb + i) * HID + colw];
        }
    }
    // stage TC table to LDS (once per block)
    {
        const int4* s4 = (const int4*)TCh;
        int4* dd4 = (int4*)TCs;
        for (int i = t; i < NCOMBO * HID * 2 / 16; i += 256) dd4[i] = s4[i];
    }
    __syncthreads();   // drains first-tile prefetch too

    for (;;) {
        int ntile = tile + AGG_GRID;
        bool more = ntile < NTILES;
        // ---- prefetch next tile (issued before AGG; hidden under it) ----
        int nv0 = 0, nq1x = 0, nq2x = 0;
        int nr0p = 0, nr1p = 0, nr2p = 0, nr3p = 0;
        float ndq1 = 0.0f, ndq2 = 0.0f, nd0 = 0.0f, nd1 = 0.0f, nd2 = 0.0f, nd3 = 0.0f;
        int ncq1 = 0, ncq2 = 0, no0 = 0, no1 = 0, no2 = 0, no3 = 0;
        if (more) {
            nv0 = ntile * 16 + w * 4;
            int nrb = rowptr[nv0 + sub] & 0xFFFFFF;
            nq1x = epack4[nrb + sl] & 0x1FFFF;
            nq2x = epack4[nrb + 16 + sl] & 0x1FFFF;
            ndq1 = dis[nq1x]; ndq2 = dis[nq2x];
            ncq1 = combo[nq1x] << 7; ncq2 = combo[nq2x] << 7;
            nr0p = __builtin_amdgcn_readfirstlane(rowptr[nv0]);
            nr1p = __builtin_amdgcn_readfirstlane(rowptr[nv0 + 1]);
            nr2p = __builtin_amdgcn_readfirstlane(rowptr[nv0 + 2]);
            nr3p = __builtin_amdgcn_readfirstlane(rowptr[nv0 + 3]);
            nd0 = dis[nv0]; nd1 = dis[nv0 + 1]; nd2 = dis[nv0 + 2]; nd3 = dis[nv0 + 3];
            no0 = combo[nv0] << 7; no1 = combo[nv0 + 1] << 7;
            no2 = combo[nv0 + 2] << 7; no3 = combo[nv0 + 3] << 7;
        }
        // ---- current tile: AGG ----
        int r0 = r0p & 0xFFFFFF, g0 = (int)((unsigned)r0p >> 24);
        int r1 = r1p & 0xFFFFFF, g1 = (int)((unsigned)r1p >> 24);
        int r2 = r2p & 0xFFFFFF, g2 = (int)((unsigned)r2p >> 24);
        int r3 = r3p & 0xFFFFFF, g3 = (int)((unsigned)r3p >> 24);
        AGG_NODE(0, r0, g0, d0, o0)
        AGG_NODE(1, r1, g1, d1, o1)
        AGG_NODE(2, r2, g2, d2, o2)
        AGG_NODE(3, r3, g3, d3, o3)
        __syncthreads();   // all 16 rows of xsA ready

        // A fragments: row = lane&15 (node), k = (lane>>4)*8 + i  (+32 for 2nd MFMA)
        const __half* xa = &xsA[lane & 15][0];
        f16x8 a0 = *(const f16x8*)(xa + (lane >> 4) * 8);
        f16x8 a1 = *(const f16x8*)(xa + 32 + (lane >> 4) * 8);
        __syncthreads();   // a-frags in regs; safe to reuse xsA as Dst
        f32x4 dacc = {0.0f, 0.0f, 0.0f, 0.0f};
        dacc = __builtin_amdgcn_mfma_f32_16x16x32_f16(a0, bf0, dacc, 0, 0, 0);
        dacc = __builtin_amdgcn_mfma_f32_16x16x32_f16(a1, bf1, dacc, 0, 0, 0);

        // D: col = lane&15 (within wave's 16-col block), row = (lane>>4)*4 + i (node)
        __half* Dst = (__half*)xsA;   // flat [16*64] reuse
        {
            int colg = (w << 4) + (lane & 15);
#pragma unroll
            for (int i = 0; i < 4; ++i)
                Dst[((lane >> 4) * 4 + i) * 64 + colg] = __float2half_rn(dacc[i]);
        }
        __syncthreads();

        // coalesced block store: 16 nodes x 64 feats fp16 = 2048 B contiguous
        {
            const uint2* ds2 = (const uint2*)Dst;
            uint2* go = (uint2*)(h2s + (size_t)tile * 16 * HID);
            go[t] = ds2[t];
        }
        if (!more) break;
        __syncthreads();   // before next tile's AGG overwrites xsA
        tile = ntile; v0 = nv0;
        q1x = nq1x; q2x = nq2x; dq1 = ndq1; dq2 = ndq2; cq1 = ncq1; cq2 = ncq2;
        r0p = nr0p; r1p = nr1p; r2p = nr2p; r3p = nr3p;
        d0 = nd0; d1 = nd1; d2 = nd2; d3 = nd3;
        o0 = no0; o1 = no1; o2 = no2; o3 = no3;
    }
}

// ---------------- per-node edge accumulate for layer 2 (16-deep MLP) ----------------
// Rows sentinel-padded to multiples of 8; sentinel h2s row is zeroed -> unmasked chunks.
__device__ __forceinline__ float agg2_node(const int* __restrict__ epack4, int sx,
                                           int rs, int deg, int lane, int lane2,
                                           const __half* __restrict__ h2s) {
    float acc = 0.0f;
    int p = rs;
    int re = rs + deg;
    for (;;) {
        int avail = re - p;
        int cnt = avail > 64 ? 64 : avail;   // multiple of 8
        int vo = sx << 7;                    // src*128 byte offset
        int j = 0;
        for (; j + 16 <= cnt; j += 16) {     // 16 loads in flight
            float g[16];
#pragma unroll
            for (int i = 0; i < 16; ++i) {
                int off = __builtin_amdgcn_readlane(vo, j + i);
                g[i] = __half2float(*(const __half*)((const char*)h2s + (off + lane2)));
            }
#pragma unroll
            for (int i = 0; i < 16; ++i) acc += g[i];
        }
        if (j < cnt) {                       // remaining 8-chunk
            float g[8];
#pragma unroll
            for (int i = 0; i < 8; ++i) {
                int off = __builtin_amdgcn_readlane(vo, j + i);
                g[i] = __half2float(*(const __half*)((const char*)h2s + (off + lane2)));
            }
#pragma unroll
            for (int i = 0; i < 8; ++i) acc += g[i];
        }
        p += 64;
        if (p >= re) break;
        sx = epack4[p + lane];
    }
    return acc;
}

// ---------------- layer-2 aggregate + pool: 4 nodes/wave, run-merged atomics ----------------
__global__ __launch_bounds__(256, 8) void agg2_pool_kernel(
    const int* __restrict__ epack4, const int* __restrict__ rowptr,
    const __half* __restrict__ h2s, const float* __restrict__ dis,
    const float* __restrict__ b2, const int* __restrict__ batch,
    float* __restrict__ pooled) {
    int t = threadIdx.x, lane = t & 63, w = t >> 6;
    int lane2 = lane * 2;
    int v0 = (blockIdx.x * 4 + w) * 4;   // grid 6250

    int r0p = __builtin_amdgcn_readfirstlane(rowptr[v0]);
    int r1p = __builtin_amdgcn_readfirstlane(rowptr[v0 + 1]);
    int r2p = __builtin_amdgcn_readfirstlane(rowptr[v0 + 2]);
    int r3p = __builtin_amdgcn_readfirstlane(rowptr[v0 + 3]);
    int r0 = r0p & 0xFFFFFF, dp0 = (int)((unsigned)r0p >> 24);
    int r1 = r1p & 0xFFFFFF, dp1 = (int)((unsigned)r1p >> 24);
    int r2 = r2p & 0xFFFFFF, dp2 = (int)((unsigned)r2p >> 24);
    int r3 = r3p & 0xFFFFFF, dp3 = (int)((unsigned)r3p >> 24);

    int sa = epack4[r0 + lane];
    int sb = epack4[r1 + lane];
    int sc = epack4[r2 + lane];
    int sd = epack4[r3 + lane];

    float bv = b2[lane];
    float acc0 = agg2_node(epack4, sa, r0, dp0, lane, lane2, h2s);
    float acc1 = agg2_node(epack4, sb, r1, dp1, lane, lane2, h2s);
    float acc2 = agg2_node(epack4, sc, r2, dp2, lane, lane2, h2s);
    float acc3 = agg2_node(epack4, sd, r3, dp3, lane, lane2, h2s);

#define AGG2_VAL(V, ACC, OUT)                                                  \
    {                                                                          \
        float dv = dis[V];                                                     \
        float self = __half2float(h2s[(size_t)(V) * HID + lane]);              \
        float val = dv * ((ACC) + self) + bv;                                  \
        OUT = val > 0.0f ? val : 0.0f;                                         \
    }
    float val0, val1, val2, val3;
    AGG2_VAL(v0, acc0, val0)
    AGG2_VAL(v0 + 1, acc1, val1)
    AGG2_VAL(v0 + 2, acc2, val2)
    AGG2_VAL(v0 + 3, acc3, val3)
#undef AGG2_VAL

    int g0 = __builtin_amdgcn_readfirstlane(batch[v0]);
    int g1 = __builtin_amdgcn_readfirstlane(batch[v0 + 1]);
    int g2 = __builtin_amdgcn_readfirstlane(batch[v0 + 2]);
    int g3 = __builtin_amdgcn_readfirstlane(batch[v0 + 3]);
    // batch is sorted: merge same-graph contributions into one atomic per run
    float s = val0; int g = g0;
    if (g1 == g) { s += val1; } else { unsafeAtomicAdd(&pooled[g * HID + lane], s); g = g1; s = val1; }
    if (g2 == g) { s += val2; } else { unsafeAtomicAdd(&pooled[g * HID + lane], s); g = g2; s = val2; }
    if (g3 == g) { s += val3; } else { unsafeAtomicAdd(&pooled[g * HID + lane], s); g = g3; s = val3; }
    unsafeAtomicAdd(&pooled[g * HID + lane], s);
}

// ---------------- logits ----------------
__global__ __launch_bounds__(64) void logits_kernel(
    const float* __restrict__ pooled, const int* __restrict__ gstart,
    const float* __restrict__ Wl, const float* __restrict__ bl,
    float* __restrict__ out) {
    __shared__ float row[HID];
    int g = blockIdx.x, t = threadIdx.x;
    int c = gstart[g + 1] - gstart[g]; if (c < 1) c = 1;
    row[t] = pooled[g * HID + t] / (float)c;
    __syncthreads();
    if (t < N_CLASSES) {
        float acc = bl[t];
#pragma unroll
        for (int k = 0; k < HID; ++k) acc = fmaf(row[k], Wl[k * N_CLASSES + t], acc);
        out[g * N_CLASSES + t] = acc;
    }
}

extern "C" void kernel_launch(void* const* d_in, const int* in_sizes, int n_in,
                              void* d_out, int out_size, void* d_ws, size_t ws_size,
                              hipStream_t stream) {
    const int*   shape_id = (const int*)d_in[0];
    const int*   color_id = (const int*)d_in[1];
    const int*   edge_idx = (const int*)d_in[2];
    const int*   batch    = (const int*)d_in[3];
    const float* st       = (const float*)d_in[4];
    const float* ct       = (const float*)d_in[5];
    const float* W1       = (const float*)d_in[6];
    const float* b1       = (const float*)d_in[7];
    const float* W2       = (const float*)d_in[8];
    const float* b2       = (const float*)d_in[9];
    const float* Wl       = (const float*)d_in[10];
    const float* bl       = (const float*)d_in[11];
    float* out = (float*)d_out;

    const int* src = edge_idx;
    const int* dst = edge_idx + N_EDGES;

    // workspace layout
    char* ws = (char*)d_ws;
    int*    combo   = (int*)   (ws + 0);            //   400,384 B (index N_NODES valid)
    float*  dis     = (float*) (ws + 400384);       //   400,384 B (index N_NODES valid)
    int*    gstart  = (int*)   (ws + 801792);       //     4,112 B
    int*    rowptr  = (int*)   (ws + 1201152);      //   400,384 B (packed rp|dp<<24)
    __half* TCh     = (__half*)(ws + 1603584);      //    19,968 B
    float*  pooled  = (float*) (ws + 1623552);      //   262,144 B
    int*    gcur    = (int*)   (ws + 1889792);      //     1,024 B
    int*    epack4  = (int*)   (ws + 1890816);      // 10,149,888 B (224 x 11328 x 4B padded)
    int*    gbin    = (int*)   (ws + 14690816);     //  7,340,032 B (packed single plane)
    __half* h2s     = (__half*)(ws + 29370880);     // 12,800,128 B (+ sentinel row)

    // 1. combo + batch boundaries + TC table + pooled/gcur/sentinel zeroing (fused)
    prep_kernel<<<SCAN_BLOCKS, 256, 0, stream>>>(shape_id, color_id, batch, combo, gstart,
                                                 st, ct, W1, TCh, pooled, gcur, h2s);

    // 2. bin edges by dst-bucket (packed single plane, vectorized loads)
    binA_kernel<<<(N_EDGES + EPB - 1) / EPB, 512, 0, stream>>>(src, dst, gcur, gbin);

    // 3. merged: degrees + dis + packed rowptr + sentinel-padded CSR scatter
    bucket_scatter_kernel<<<NBUCK, 1024, 0, stream>>>(gbin, gcur, dis, rowptr, epack4);

    // 4. fused layer-1 aggregate + MFMA mm2 -> h2s (persistent 2-tile blocks)
    agg1_mm2_kernel<<<AGG_GRID, 256, 0, stream>>>(epack4, rowptr, combo, dis, TCh, W2, b1, h2s);

    // 5. layer-2 aggregate + pool (16-deep gather pipelines)
    agg2_pool_kernel<<<6250, 256, 0, stream>>>(epack4, rowptr, h2s, dis, b2, batch, pooled);

    // 6. logits (counts from gstart boundaries)
    logits_kernel<<<N_GRAPHS, 64, 0, stream>>>(pooled, gstart, Wl, bl, out);
}